// Round 6
// baseline (1390.082 us; speedup 1.0000x reference)
//
#include <hip/hip_runtime.h>

// MemoryAugmentation: value[b,c] = softmax_m(x[b,c] . mem[m]) . mem
// B*C = 8192 rows, H*W = 7744 (= 1936 float4), M = 10 slots.
//
// R6: phase-staggered blocks. R3 (88.45us) ran all 2048 blocks in lockstep:
// ~40us all-read phase1, then ~45us all-write phase2 -> HBM never sees the
// mixed R/W stream that reaches 6.3 TB/s (copy ubench). Now each block owns
// TWO 4-row groups; a 1-bit role (global atomic ticket, order-only ->
// deterministic output) picks [P1a P2a P1b P2b] vs [P1a P1b P2a P2b] so
// ~half the active blocks read while the other half write.
// 512 thr (8 waves), grid 1024 = 4 blocks/CU, __launch_bounds__(512,8)
// forces the 64-VGPR tier (R5 showed the 128 tier loses to TLP).
// mem L2 traffic unchanged: 310KB per group-pass, groups of 4 rows.

#define RROWS   4             // rows per group
#define NGROUP  2             // groups per block
#define NM      10
#define NVEC    1936          // 7744 / 4 float4 per row
#define THREADS 512
#define NWAVES  (THREADS / 64)

typedef float f32x4 __attribute__((ext_vector_type(4)));

__global__ __launch_bounds__(THREADS, 8)
void memaug_kernel(const float* __restrict__ x,
                   const float* __restrict__ mem,
                   float* __restrict__ out,
                   unsigned* __restrict__ ticket)
{
    __shared__ float red[NWAVES][RROWS][NM];
    __shared__ float prob[NGROUP][RROWS][NM];
    __shared__ unsigned role_sh;

    const int tid  = threadIdx.x;
    const int wave = tid >> 6;
    const int lane = tid & 63;
    const long rowbase = (long)blockIdx.x * (RROWS * NGROUP);

    if (tid == 0) role_sh = atomicAdd(ticket, 1u) & 1u;
    __syncthreads();
    const unsigned role = role_sh;

    const f32x4* __restrict__ m4 = (const f32x4*)mem;

    // ---------- P1(g): scores + softmax -> prob[g] ----------
    auto P1 = [&](int g) {
        const f32x4* __restrict__ xr =
            (const f32x4*)x + (rowbase + (long)g * RROWS) * NVEC;

        float acc[RROWS][NM];
#pragma unroll
        for (int j = 0; j < RROWS; ++j)
#pragma unroll
            for (int m = 0; m < NM; ++m) acc[j][m] = 0.f;

        for (int iv = tid; iv < NVEC; iv += THREADS) {
            f32x4 xv[RROWS];
#pragma unroll
            for (int j = 0; j < RROWS; ++j)
                xv[j] = xr[j * NVEC + iv];
            f32x4 mv[NM];
#pragma unroll
            for (int m = 0; m < NM; ++m)
                mv[m] = m4[m * NVEC + iv];
#pragma unroll
            for (int m = 0; m < NM; ++m)
#pragma unroll
                for (int j = 0; j < RROWS; ++j)
                    acc[j][m] += xv[j].x * mv[m].x + xv[j].y * mv[m].y
                               + xv[j].z * mv[m].z + xv[j].w * mv[m].w;
        }

        // 64-lane butterfly
#pragma unroll
        for (int j = 0; j < RROWS; ++j)
#pragma unroll
            for (int m = 0; m < NM; ++m) {
                float v = acc[j][m];
#pragma unroll
                for (int off = 32; off > 0; off >>= 1)
                    v += __shfl_xor(v, off, 64);
                acc[j][m] = v;
            }

        if (lane == 0) {
#pragma unroll
            for (int j = 0; j < RROWS; ++j)
#pragma unroll
                for (int m = 0; m < NM; ++m) red[wave][j][m] = acc[j][m];
        }
        __syncthreads();

        if (tid < RROWS) {
            const int j = tid;
            float s[NM];
            float mx = -1e30f;
#pragma unroll
            for (int m = 0; m < NM; ++m) {
                float v = 0.f;
#pragma unroll
                for (int w = 0; w < NWAVES; ++w) v += red[w][j][m];
                s[m] = v;
                mx = fmaxf(mx, v);
            }
            float sum = 0.f;
#pragma unroll
            for (int m = 0; m < NM; ++m) { s[m] = expf(s[m] - mx); sum += s[m]; }
            const float inv = 1.f / sum;
#pragma unroll
            for (int m = 0; m < NM; ++m) prob[g][j][m] = s[m] * inv;
        }
        __syncthreads();
    };

    // ---------- P2(g): out rows = sum_m prob[g][m] * mem ----------
    auto P2 = [&](int g) {
        f32x4* __restrict__ orow =
            (f32x4*)out + (rowbase + (long)g * RROWS) * NVEC;

        float p[RROWS][NM];
#pragma unroll
        for (int j = 0; j < RROWS; ++j)
#pragma unroll
            for (int m = 0; m < NM; ++m) p[j][m] = prob[g][j][m];

        for (int iv = tid; iv < NVEC; iv += THREADS) {
            f32x4 mv[NM];
#pragma unroll
            for (int m = 0; m < NM; ++m)
                mv[m] = m4[m * NVEC + iv];

            f32x4 ov[RROWS];
#pragma unroll
            for (int j = 0; j < RROWS; ++j) {
                ov[j] = mv[0] * p[j][0];
#pragma unroll
                for (int m = 1; m < NM; ++m) ov[j] += mv[m] * p[j][m];
            }
#pragma unroll
            for (int j = 0; j < RROWS; ++j)
                __builtin_nontemporal_store(ov[j], &orow[j * NVEC + iv]);
        }
    };

    if (role == 0) {
        P1(0); P2(0); P1(1); P2(1);
    } else {
        P1(0); P1(1); P2(0); P2(1);
    }
}

extern "C" void kernel_launch(void* const* d_in, const int* in_sizes, int n_in,
                              void* d_out, int out_size, void* d_ws, size_t ws_size,
                              hipStream_t stream) {
    const float* x   = (const float*)d_in[0];   // [32,256,88,88] f32
    const float* mem = (const float*)d_in[1];   // [10,88,88] f32
    float* out       = (float*)d_out;           // [32,256,88,88] f32
    unsigned* ticket = (unsigned*)d_ws;         // order-only; any start value ok

    const int rows   = 32 * 256;                    // 8192
    const int blocks = rows / (RROWS * NGROUP);     // 1024

    memaug_kernel<<<blocks, THREADS, 0, stream>>>(x, mem, out, ticket);
}

// Round 7
// 157.135 us; speedup vs baseline: 8.8464x; 8.8464x over previous
//
#include <hip/hip_runtime.h>

// MemoryAugmentation: value[b,c] = softmax_m(x[b,c] . mem[m]) . mem
// B*C = 8192 rows, row length H*W = 7744 (= 1936 float4), M = 10 slots.
// One block of 256 threads handles R=4 consecutive rows.
//
// R7 = R3 (88.45us, best known) with ONE change: plain stores instead of
// __builtin_nontemporal_store. A/B on the write path: R0/R3 FETCH_SIZE
// identical (125.8/125.6 MB) proves nt gains nothing on L3 x-residency;
// if nt's L2-bypass costs write BW (~4.5 vs 6.3 TB/s would explain the
// 88-vs-73 gap), plain stores recover it.
// Register discipline (R4/R6 lessons): stay in the 64-VGPR tier, no
// explicit double-buffering, no launch-bounds min-waves forcing.

#define RROWS   4
#define NM      10
#define NVEC    1936          // 7744 / 4 float4 per row
#define THREADS 256

typedef float f32x4 __attribute__((ext_vector_type(4)));

__global__ __launch_bounds__(THREADS)
void memaug_kernel(const float* __restrict__ x,
                   const float* __restrict__ mem,
                   float* __restrict__ out)
{
    const int tid = threadIdx.x;
    const long r0 = (long)blockIdx.x * RROWS;   // first row of this block

    const f32x4* __restrict__ m4  = (const f32x4*)mem;
    const f32x4* __restrict__ xr  = (const f32x4*)x + r0 * NVEC;
    f32x4* __restrict__ orow      = (f32x4*)out + r0 * NVEC;

    // ---------------- Phase 1: scores[j][m] = x_row_j . mem_m ----------------
    float acc[RROWS][NM];
#pragma unroll
    for (int j = 0; j < RROWS; ++j)
#pragma unroll
        for (int m = 0; m < NM; ++m) acc[j][m] = 0.f;

    for (int iv = tid; iv < NVEC; iv += THREADS) {
        // issue ALL loads first so they are concurrently outstanding
        f32x4 xv[RROWS];
#pragma unroll
        for (int j = 0; j < RROWS; ++j)
            xv[j] = xr[j * NVEC + iv];
        f32x4 mv[NM];
#pragma unroll
        for (int m = 0; m < NM; ++m)
            mv[m] = m4[m * NVEC + iv];
#pragma unroll
        for (int m = 0; m < NM; ++m) {
#pragma unroll
            for (int j = 0; j < RROWS; ++j) {
                acc[j][m] += xv[j].x * mv[m].x + xv[j].y * mv[m].y
                           + xv[j].z * mv[m].z + xv[j].w * mv[m].w;
            }
        }
    }

    // Wave-level butterfly reduce (64 lanes)
#pragma unroll
    for (int j = 0; j < RROWS; ++j)
#pragma unroll
        for (int m = 0; m < NM; ++m) {
            float v = acc[j][m];
#pragma unroll
            for (int off = 32; off > 0; off >>= 1)
                v += __shfl_xor(v, off, 64);
            acc[j][m] = v;
        }

    __shared__ float red[4][RROWS][NM];   // per-wave partials
    __shared__ float prob[RROWS][NM];     // softmax probabilities

    const int wave = tid >> 6;
    const int lane = tid & 63;
    if (lane == 0) {
#pragma unroll
        for (int j = 0; j < RROWS; ++j)
#pragma unroll
            for (int m = 0; m < NM; ++m) red[wave][j][m] = acc[j][m];
    }
    __syncthreads();

    // ---------------- Softmax over m (threads 0..RROWS-1) ----------------
    if (tid < RROWS) {
        const int j = tid;
        float s[NM];
        float mx = -1e30f;
#pragma unroll
        for (int m = 0; m < NM; ++m) {
            s[m] = red[0][j][m] + red[1][j][m] + red[2][j][m] + red[3][j][m];
            mx = fmaxf(mx, s[m]);
        }
        float sum = 0.f;
#pragma unroll
        for (int m = 0; m < NM; ++m) { s[m] = expf(s[m] - mx); sum += s[m]; }
        const float inv = 1.f / sum;
#pragma unroll
        for (int m = 0; m < NM; ++m) prob[j][m] = s[m] * inv;
    }
    __syncthreads();

    float p[RROWS][NM];
#pragma unroll
    for (int j = 0; j < RROWS; ++j)
#pragma unroll
        for (int m = 0; m < NM; ++m) p[j][m] = prob[j][m];

    // ---------------- Phase 2: out_row_j = sum_m p[j][m] * mem_m ----------------
    for (int iv = tid; iv < NVEC; iv += THREADS) {
        f32x4 mv[NM];
#pragma unroll
        for (int m = 0; m < NM; ++m)
            mv[m] = m4[m * NVEC + iv];

        f32x4 ov[RROWS];
#pragma unroll
        for (int j = 0; j < RROWS; ++j) {
            ov[j] = mv[0] * p[j][0];
#pragma unroll
            for (int m = 1; m < NM; ++m) ov[j] += mv[m] * p[j][m];
        }
#pragma unroll
        for (int j = 0; j < RROWS; ++j)
            orow[j * NVEC + iv] = ov[j];
    }
}

extern "C" void kernel_launch(void* const* d_in, const int* in_sizes, int n_in,
                              void* d_out, int out_size, void* d_ws, size_t ws_size,
                              hipStream_t stream) {
    const float* x   = (const float*)d_in[0];   // [32,256,88,88] f32
    const float* mem = (const float*)d_in[1];   // [10,88,88] f32
    float* out       = (float*)d_out;           // [32,256,88,88] f32

    const int rows   = 32 * 256;                // 8192
    const int blocks = rows / RROWS;            // 2048

    memaug_kernel<<<blocks, THREADS, 0, stream>>>(x, mem, out);
}

// Round 8
// 92.676 us; speedup vs baseline: 14.9993x; 1.6955x over previous
//
#include <hip/hip_runtime.h>

// MemoryAugmentation: value[b,c] = softmax_m(x[b,c] . mem[m]) . mem
// B*C = 8192 rows, H*W = 7744 (= 1936 float4), M = 10 slots.
//
// R8: phase stagger, register-safe. R6's test died of a (512,8)->32-reg
// spill; this retry keeps R3's EXACT 64-reg phase bodies (component-wise
// FMA, nt stores, bare launch_bounds(256)) and adds only:
//   - NGROUP=2 row-groups per block (grid 1024)
//   - role=(blockIdx>>3)&1: role0 = P1a P2a P1b P2b, role1 = P1a P1b P2a P2b
// so at steady state ~half the blocks read x while half write out ->
// mixed R/W stream at HBM. Deterministic (no atomics).
// Lessons enforced: 64-VGPR tier only; nt stores; component-wise FMA form
// (vector-op form allocates 128 regs: R5/R7).

#define RROWS   4
#define NGROUP  2
#define NM      10
#define NVEC    1936          // 7744 / 4 float4 per row
#define THREADS 256

typedef float f32x4 __attribute__((ext_vector_type(4)));

__global__ __launch_bounds__(THREADS)
void memaug_kernel(const float* __restrict__ x,
                   const float* __restrict__ mem,
                   float* __restrict__ out)
{
    const int tid  = threadIdx.x;
    const int wave = tid >> 6;
    const int lane = tid & 63;
    const long rowbase = (long)blockIdx.x * (RROWS * NGROUP);
    const unsigned role = (blockIdx.x >> 3) & 1u;

    const f32x4* __restrict__ m4 = (const f32x4*)mem;

    __shared__ float red[4][RROWS][NM];
    __shared__ float prob[NGROUP][RROWS][NM];

    // ---------- P1(g): scores + softmax -> prob[g] (exact R3 body) ----------
    auto P1 = [&](int g) {
        const f32x4* __restrict__ xr =
            (const f32x4*)x + (rowbase + (long)g * RROWS) * NVEC;

        float acc[RROWS][NM];
#pragma unroll
        for (int j = 0; j < RROWS; ++j)
#pragma unroll
            for (int m = 0; m < NM; ++m) acc[j][m] = 0.f;

        for (int iv = tid; iv < NVEC; iv += THREADS) {
            f32x4 xv[RROWS];
#pragma unroll
            for (int j = 0; j < RROWS; ++j)
                xv[j] = xr[j * NVEC + iv];
            f32x4 mv[NM];
#pragma unroll
            for (int m = 0; m < NM; ++m)
                mv[m] = m4[m * NVEC + iv];
#pragma unroll
            for (int m = 0; m < NM; ++m) {
#pragma unroll
                for (int j = 0; j < RROWS; ++j) {
                    acc[j][m] += xv[j].x * mv[m].x + xv[j].y * mv[m].y
                               + xv[j].z * mv[m].z + xv[j].w * mv[m].w;
                }
            }
        }

#pragma unroll
        for (int j = 0; j < RROWS; ++j)
#pragma unroll
            for (int m = 0; m < NM; ++m) {
                float v = acc[j][m];
#pragma unroll
                for (int off = 32; off > 0; off >>= 1)
                    v += __shfl_xor(v, off, 64);
                acc[j][m] = v;
            }

        if (lane == 0) {
#pragma unroll
            for (int j = 0; j < RROWS; ++j)
#pragma unroll
                for (int m = 0; m < NM; ++m) red[wave][j][m] = acc[j][m];
        }
        __syncthreads();

        if (tid < RROWS) {
            const int j = tid;
            float s[NM];
            float mx = -1e30f;
#pragma unroll
            for (int m = 0; m < NM; ++m) {
                s[m] = red[0][j][m] + red[1][j][m] + red[2][j][m] + red[3][j][m];
                mx = fmaxf(mx, s[m]);
            }
            float sum = 0.f;
#pragma unroll
            for (int m = 0; m < NM; ++m) { s[m] = expf(s[m] - mx); sum += s[m]; }
            const float inv = 1.f / sum;
#pragma unroll
            for (int m = 0; m < NM; ++m) prob[g][j][m] = s[m] * inv;
        }
        __syncthreads();
    };

    // ---------- P2(g): out rows (exact R3 body: component-wise, nt) ----------
    auto P2 = [&](int g) {
        f32x4* __restrict__ orow =
            (f32x4*)out + (rowbase + (long)g * RROWS) * NVEC;

        float p[RROWS][NM];
#pragma unroll
        for (int j = 0; j < RROWS; ++j)
#pragma unroll
            for (int m = 0; m < NM; ++m) p[j][m] = prob[g][j][m];

        for (int iv = tid; iv < NVEC; iv += THREADS) {
            f32x4 mv[NM];
#pragma unroll
            for (int m = 0; m < NM; ++m)
                mv[m] = m4[m * NVEC + iv];

            f32x4 ov[RROWS];
#pragma unroll
            for (int j = 0; j < RROWS; ++j) ov[j] = (f32x4)(0.f);
#pragma unroll
            for (int m = 0; m < NM; ++m) {
#pragma unroll
                for (int j = 0; j < RROWS; ++j) {
                    ov[j].x += p[j][m] * mv[m].x;
                    ov[j].y += p[j][m] * mv[m].y;
                    ov[j].z += p[j][m] * mv[m].z;
                    ov[j].w += p[j][m] * mv[m].w;
                }
            }
#pragma unroll
            for (int j = 0; j < RROWS; ++j)
                __builtin_nontemporal_store(ov[j], &orow[j * NVEC + iv]);
        }
    };

    if (role == 0) {
        P1(0); P2(0); P1(1); P2(1);
    } else {
        P1(0); P1(1); P2(0); P2(1);
    }
}

extern "C" void kernel_launch(void* const* d_in, const int* in_sizes, int n_in,
                              void* d_out, int out_size, void* d_ws, size_t ws_size,
                              hipStream_t stream) {
    const float* x   = (const float*)d_in[0];   // [32,256,88,88] f32
    const float* mem = (const float*)d_in[1];   // [10,88,88] f32
    float* out       = (float*)d_out;           // [32,256,88,88] f32

    const int rows   = 32 * 256;                    // 8192
    const int blocks = rows / (RROWS * NGROUP);     // 1024

    memaug_kernel<<<blocks, THREADS, 0, stream>>>(x, mem, out);
}